// Round 1
// baseline (347.090 us; speedup 1.0000x reference)
//
#include <hip/hip_runtime.h>
#include <math.h>

constexpr int NB = 16;    // batch
constexpr int SL = 1024;  // L
constexpr int ND = 128;   // D
constexpr int NH = 256;   // H

// ws layout (float indices)
constexpr int P_OFF     = 0;                       // [2][NB][8][ND] partial sums
constexpr int SCALE_OFF = 2 * NB * 8 * ND;         // [NB][ND]
constexpr int BIAS_OFF  = SCALE_OFF + NB * ND;     // [NB][ND]
constexpr int FILT_OFF  = BIAS_OFF + NB * ND;      // [NB][SL][ND] float2

// ---------------- K1: partial sums of y and z over t ----------------
__global__ __launch_bounds__(256) void k_partial(const float* __restrict__ y,
                                                 const float* __restrict__ z,
                                                 float* __restrict__ ws) {
    // grid: 2*NB*8 blocks
    const int blk = blockIdx.x;
    const int ch  = blk & 7;
    const int b   = (blk >> 3) & 15;
    const int src = blk >> 7;
    const float* base = (src == 0 ? y : z) + (size_t)b * SL * ND;
    const int d    = threadIdx.x & 127;
    const int half = threadIdx.x >> 7;
    float s = 0.f;
    const int t0 = ch * 128 + half;
    for (int t = 0; t < 128; t += 2)
        s += base[(size_t)(t0 + t) * ND + d];
    __shared__ float red[256];
    red[threadIdx.x] = s;
    __syncthreads();
    if (half == 0)
        ws[P_OFF + ((size_t)(src * NB + b) * 8 + ch) * ND + d] = s + red[d + 128];
}

// ---------------- K2: MLPs -> scale/bias ----------------
__global__ __launch_bounds__(256) void k_mlp(
    float* __restrict__ ws,
    const int* __restrict__ len_y, const int* __restrict__ len_z,
    const float* __restrict__ W1w1, const float* __restrict__ W1b1,
    const float* __restrict__ W1w2, const float* __restrict__ W1b2,
    const float* __restrict__ B1w1, const float* __restrict__ B1b1,
    const float* __restrict__ B1w2, const float* __restrict__ B1b2,
    const float* __restrict__ W2w1, const float* __restrict__ W2b1,
    const float* __restrict__ W2w2, const float* __restrict__ W2b2,
    const float* __restrict__ B2w1, const float* __restrict__ B2b1,
    const float* __restrict__ B2w2, const float* __restrict__ B2b2) {
    const int b = blockIdx.x;
    const int tid = threadIdx.x;
    __shared__ float c1[ND], c2[ND];
    __shared__ float h[4][NH];
    __shared__ float o[4][ND];

    if (tid < ND) {
        float s = 0.f;
        for (int ch = 0; ch < 8; ++ch)
            s += ws[P_OFF + ((size_t)(0 * NB + b) * 8 + ch) * ND + tid];
        c1[tid] = s / (float)len_y[b];
    } else {
        const int d = tid - ND;
        float s = 0.f;
        for (int ch = 0; ch < 8; ++ch)
            s += ws[P_OFF + ((size_t)(1 * NB + b) * 8 + ch) * ND + d];
        c2[d] = s / (float)len_z[b];
    }
    __syncthreads();

    const float* w1s[4] = {W1w1, B1w1, W2w1, B2w1};
    const float* b1s[4] = {W1b1, B1b1, W2b1, B2b1};
    const float* w2s[4] = {W1w2, B1w2, W2w2, B2w2};
    const float* b2s[4] = {W1b2, B1b2, W2b2, B2b2};

    for (int m = 0; m < 4; ++m) {
        const float* c = (m < 2) ? c1 : c2;   // W1,B1 use c1; W2,B2 use c2
        const float* w = w1s[m];
        const int j = tid;                    // NH == blockDim
        float s = b1s[m][j];
        for (int i = 0; i < ND; ++i)
            s = fmaf(c[i], w[i * NH + j], s);
        // exact gelu: x * 0.5 * (1 + erf(x/sqrt(2)))
        h[m][j] = 0.5f * s * (1.f + erff(s * 0.7071067811865475f));
    }
    __syncthreads();

    for (int p = tid; p < 4 * ND; p += 256) {
        const int m = p >> 7, d = p & 127;
        const float* w = w2s[m];
        float s = b2s[m][d];
        for (int j = 0; j < NH; ++j)
            s = fmaf(h[m][j], w[j * ND + d], s);
        o[m][d] = s;
    }
    __syncthreads();

    if (tid < ND) {
        ws[SCALE_OFF + b * ND + tid] = 1.f + 0.5f * (o[0][tid] + o[2][tid]);
        ws[BIAS_OFF  + b * ND + tid] = 0.5f * (o[1][tid] + o[3][tid]);
    }
}

// ---------------- K3: forward DFT + real filter ----------------
__global__ __launch_bounds__(256) void k_fwd(const float* __restrict__ x,
                                             const int* __restrict__ len_x,
                                             const float* __restrict__ ws_ro,
                                             float* __restrict__ ws) {
    const int b = blockIdx.x >> 5;
    const int ktile = blockIdx.x & 31;
    const int l = len_x[b];
    const int kbase = ktile * 32;
    if (kbase >= l) return;
    const unsigned ul = (unsigned)l;

    __shared__ float2 tw[SL];
    __shared__ float xs[64][ND];

    const int tid = threadIdx.x;
    {
        const float cang = -6.283185307179586f / (float)l;
        for (int j = tid; j < l; j += 256) {
            float s, c;
            sincosf((float)j * cang, &s, &c);
            tw[j] = make_float2(c, s);
        }
    }

    const int kq = tid >> 5;
    const int dq = tid & 31;
    const int d0 = dq << 2;

    int kk[4]; unsigned idx[4]; bool act[4];
#pragma unroll
    for (int i = 0; i < 4; ++i) {
        const int k = kbase + kq + 8 * i;
        act[i] = (k < l);
        kk[i] = act[i] ? k : 0;
        idx[i] = 0u;
    }
    float ar[4][4] = {}, ai[4][4] = {};

    for (int t0 = 0; t0 < l; t0 += 64) {
        const int tt = min(64, l - t0);
        __syncthreads();
        for (int r = tid; r < 64 * 32; r += 256) {
            const int row = r >> 5, c4 = (r & 31) << 2;
            *(float4*)&xs[row][c4] =
                *(const float4*)&x[((size_t)b * SL + (size_t)(t0 + row)) * ND + c4];
        }
        __syncthreads();
        for (int t = 0; t < tt; ++t) {
            const float4 xv = *(const float4*)&xs[t][d0];
#pragma unroll
            for (int i = 0; i < 4; ++i) {
                const float2 w = tw[idx[i]];
                const unsigned a = idx[i] + (unsigned)kk[i];
                idx[i] = (a < ul) ? a : (a - ul);
                ar[i][0] = fmaf(w.x, xv.x, ar[i][0]);
                ai[i][0] = fmaf(w.y, xv.x, ai[i][0]);
                ar[i][1] = fmaf(w.x, xv.y, ar[i][1]);
                ai[i][1] = fmaf(w.y, xv.y, ai[i][1]);
                ar[i][2] = fmaf(w.x, xv.z, ar[i][2]);
                ai[i][2] = fmaf(w.y, xv.z, ai[i][2]);
                ar[i][3] = fmaf(w.x, xv.w, ar[i][3]);
                ai[i][3] = fmaf(w.y, xv.w, ai[i][3]);
            }
        }
    }

    const float4 sc = *(const float4*)&ws_ro[SCALE_OFF + b * ND + d0];
    const float4 bi = *(const float4*)&ws_ro[BIAS_OFF + b * ND + d0];
#pragma unroll
    for (int i = 0; i < 4; ++i) {
        if (!act[i]) continue;
        float* p = &ws[FILT_OFF + (((size_t)b * SL + (size_t)kk[i]) * ND + d0) * 2];
        const float4 lo = make_float4(fmaf(ar[i][0], sc.x, bi.x), ai[i][0] * sc.x,
                                      fmaf(ar[i][1], sc.y, bi.y), ai[i][1] * sc.y);
        const float4 hi = make_float4(fmaf(ar[i][2], sc.z, bi.z), ai[i][2] * sc.z,
                                      fmaf(ar[i][3], sc.w, bi.w), ai[i][3] * sc.w);
        *(float4*)p = lo;
        *(float4*)(p + 4) = hi;
    }
}

// ---------------- K4: inverse DFT, real part only ----------------
__global__ __launch_bounds__(256) void k_inv(const float* __restrict__ ws,
                                             const int* __restrict__ len_x,
                                             float* __restrict__ out) {
    const int b = blockIdx.x >> 5;
    const int ktile = blockIdx.x & 31;
    const int l = len_x[b];
    const int kbase = ktile * 32;
    if (kbase >= l) return;
    const unsigned ul = (unsigned)l;

    __shared__ float2 tw[SL];
    __shared__ float2 fs[32][ND];

    const int tid = threadIdx.x;
    {
        const float cang = 6.283185307179586f / (float)l;
        for (int j = tid; j < l; j += 256) {
            float s, c;
            sincosf((float)j * cang, &s, &c);
            tw[j] = make_float2(c, s);
        }
    }

    const int kq = tid >> 5;
    const int dq = tid & 31;
    const int d0 = dq << 2;

    int kk[4]; unsigned idx[4]; bool act[4];
#pragma unroll
    for (int i = 0; i < 4; ++i) {
        const int k = kbase + kq + 8 * i;
        act[i] = (k < l);
        kk[i] = act[i] ? k : 0;
        idx[i] = 0u;
    }
    float ar[4][4] = {};

    for (int t0 = 0; t0 < l; t0 += 32) {
        const int tt = min(32, l - t0);
        __syncthreads();
        for (int r = tid; r < 32 * 64; r += 256) {
            const int row = r >> 6, c4 = (r & 63) << 2;
            *(float4*)((float*)&fs[row][0] + c4) =
                *(const float4*)&ws[FILT_OFF + (((size_t)b * SL + (size_t)(t0 + row)) * ND) * 2 + c4];
        }
        __syncthreads();
        for (int t = 0; t < tt; ++t) {
            const float4 f01 = *(const float4*)&fs[t][d0];
            const float4 f23 = *(const float4*)&fs[t][d0 + 2];
#pragma unroll
            for (int i = 0; i < 4; ++i) {
                const float2 w = tw[idx[i]];
                const unsigned a = idx[i] + (unsigned)kk[i];
                idx[i] = (a < ul) ? a : (a - ul);
                ar[i][0] = fmaf(w.x, f01.x, ar[i][0]);
                ar[i][0] = fmaf(-w.y, f01.y, ar[i][0]);
                ar[i][1] = fmaf(w.x, f01.z, ar[i][1]);
                ar[i][1] = fmaf(-w.y, f01.w, ar[i][1]);
                ar[i][2] = fmaf(w.x, f23.x, ar[i][2]);
                ar[i][2] = fmaf(-w.y, f23.y, ar[i][2]);
                ar[i][3] = fmaf(w.x, f23.z, ar[i][3]);
                ar[i][3] = fmaf(-w.y, f23.w, ar[i][3]);
            }
        }
    }

    const float invl = 1.f / (float)l;
#pragma unroll
    for (int i = 0; i < 4; ++i) {
        if (!act[i]) continue;
        const float4 v = make_float4(ar[i][0] * invl, ar[i][1] * invl,
                                     ar[i][2] * invl, ar[i][3] * invl);
        *(float4*)&out[((size_t)b * SL + (size_t)kk[i]) * ND + d0] = v;
    }
}

extern "C" void kernel_launch(void* const* d_in, const int* in_sizes, int n_in,
                              void* d_out, int out_size, void* d_ws, size_t ws_size,
                              hipStream_t stream) {
    const float* x = (const float*)d_in[0];
    const float* y = (const float*)d_in[1];
    const float* z = (const float*)d_in[2];
    const int* len_x = (const int*)d_in[3];
    const int* len_y = (const int*)d_in[4];
    const int* len_z = (const int*)d_in[5];
    float* ws = (float*)d_ws;
    float* out = (float*)d_out;

    k_partial<<<2 * NB * 8, 256, 0, stream>>>(y, z, ws);

    k_mlp<<<NB, 256, 0, stream>>>(ws, len_y, len_z,
        (const float*)d_in[6],  (const float*)d_in[7],  (const float*)d_in[8],  (const float*)d_in[9],
        (const float*)d_in[10], (const float*)d_in[11], (const float*)d_in[12], (const float*)d_in[13],
        (const float*)d_in[14], (const float*)d_in[15], (const float*)d_in[16], (const float*)d_in[17],
        (const float*)d_in[18], (const float*)d_in[19], (const float*)d_in[20], (const float*)d_in[21]);

    k_fwd<<<NB * 32, 256, 0, stream>>>(x, len_x, ws, ws);

    hipMemsetAsync(d_out, 0, (size_t)NB * SL * ND * sizeof(float), stream);

    k_inv<<<NB * 32, 256, 0, stream>>>(ws, len_x, out);
}

// Round 2
// 292.617 us; speedup vs baseline: 1.1862x; 1.1862x over previous
//
#include <hip/hip_runtime.h>
#include <math.h>

constexpr int NB = 16;    // batch
constexpr int SL = 1024;  // L
constexpr int ND = 128;   // D
constexpr int NH = 256;   // H

// ws layout (float indices)
constexpr int P_OFF     = 0;                       // [2][NB][8][ND] partial sums
constexpr int SCALE_OFF = 2 * NB * 8 * ND;         // [NB][ND]
constexpr int BIAS_OFF  = SCALE_OFF + NB * ND;     // [NB][ND]
constexpr int FILTR_OFF = BIAS_OFF + NB * ND;      // [NB][SL][ND] real plane
constexpr int FILTI_OFF = FILTR_OFF + NB * SL * ND; // [NB][SL][ND] imag plane

constexpr float TWO_PI = 6.283185307179586f;

// ---------------- K1: partial sums of y and z over t ----------------
__global__ __launch_bounds__(256) void k_partial(const float* __restrict__ y,
                                                 const float* __restrict__ z,
                                                 float* __restrict__ ws) {
    const int blk = blockIdx.x;
    const int ch  = blk & 7;
    const int b   = (blk >> 3) & 15;
    const int src = blk >> 7;
    const float* base = (src == 0 ? y : z) + (size_t)b * SL * ND;
    const int d    = threadIdx.x & 127;
    const int half = threadIdx.x >> 7;
    float s = 0.f;
    const int t0 = ch * 128 + half;
    for (int t = 0; t < 128; t += 2)
        s += base[(size_t)(t0 + t) * ND + d];
    __shared__ float red[256];
    red[threadIdx.x] = s;
    __syncthreads();
    if (half == 0)
        ws[P_OFF + ((size_t)(src * NB + b) * 8 + ch) * ND + d] = s + red[d + 128];
}

// ---------------- K2: MLPs -> scale/bias ----------------
__global__ __launch_bounds__(256) void k_mlp(
    float* __restrict__ ws,
    const int* __restrict__ len_y, const int* __restrict__ len_z,
    const float* __restrict__ W1w1, const float* __restrict__ W1b1,
    const float* __restrict__ W1w2, const float* __restrict__ W1b2,
    const float* __restrict__ B1w1, const float* __restrict__ B1b1,
    const float* __restrict__ B1w2, const float* __restrict__ B1b2,
    const float* __restrict__ W2w1, const float* __restrict__ W2b1,
    const float* __restrict__ W2w2, const float* __restrict__ W2b2,
    const float* __restrict__ B2w1, const float* __restrict__ B2b1,
    const float* __restrict__ B2w2, const float* __restrict__ B2b2) {
    const int b = blockIdx.x;
    const int tid = threadIdx.x;
    __shared__ float c1[ND], c2[ND];
    __shared__ float h[4][NH];
    __shared__ float o[4][ND];

    if (tid < ND) {
        float s = 0.f;
        for (int ch = 0; ch < 8; ++ch)
            s += ws[P_OFF + ((size_t)(0 * NB + b) * 8 + ch) * ND + tid];
        c1[tid] = s / (float)len_y[b];
    } else {
        const int d = tid - ND;
        float s = 0.f;
        for (int ch = 0; ch < 8; ++ch)
            s += ws[P_OFF + ((size_t)(1 * NB + b) * 8 + ch) * ND + d];
        c2[d] = s / (float)len_z[b];
    }
    __syncthreads();

    const float* w1s[4] = {W1w1, B1w1, W2w1, B2w1};
    const float* b1s[4] = {W1b1, B1b1, W2b1, B2b1};
    const float* w2s[4] = {W1w2, B1w2, W2w2, B2w2};
    const float* b2s[4] = {W1b2, B1b2, W2b2, B2b2};

    for (int m = 0; m < 4; ++m) {
        const float* c = (m < 2) ? c1 : c2;
        const float* w = w1s[m];
        const int j = tid;
        float s = b1s[m][j];
        for (int i = 0; i < ND; ++i)
            s = fmaf(c[i], w[i * NH + j], s);
        h[m][j] = 0.5f * s * (1.f + erff(s * 0.7071067811865475f));
    }
    __syncthreads();

    for (int p = tid; p < 4 * ND; p += 256) {
        const int m = p >> 7, d = p & 127;
        const float* w = w2s[m];
        float s = b2s[m][d];
        for (int j = 0; j < NH; ++j)
            s = fmaf(h[m][j], w[j * ND + d], s);
        o[m][d] = s;
    }
    __syncthreads();

    if (tid < ND) {
        ws[SCALE_OFF + b * ND + tid] = 1.f + 0.5f * (o[0][tid] + o[2][tid]);
        ws[BIAS_OFF  + b * ND + tid] = 0.5f * (o[1][tid] + o[3][tid]);
    }
}

// ---------------- K3: forward DFT + real filter ----------------
// grid: NB*64 blocks; each block: 16 k-rows, all t, all 128 d.
// thread: kq = tid>>4 (k within tile), dq = tid&15 -> d-quads at dq*4 and 64+dq*4.
__global__ __launch_bounds__(256) void k_fwd(const float* __restrict__ x,
                                             const int* __restrict__ len_x,
                                             const float* __restrict__ ws_ro,
                                             float* __restrict__ ws) {
    const int b = blockIdx.x >> 6;
    const int ktile = blockIdx.x & 63;
    const int l = len_x[b];
    const int kbase = ktile * 16;
    if (kbase >= l) return;

    const int tid = threadIdx.x;
    const int kq = tid >> 4;
    const int dq = tid & 15;
    const int k = kbase + kq;
    const bool act = (k < l);
    const int kc = act ? k : 0;
    const int d0a = dq * 4, d0b = 64 + dq * 4;
    const float invl = 1.f / (float)l;

    __shared__ float xs[64][ND];

    // per-step twiddle: e^{-2*pi*i*k/l}
    float sim, sre;
    sincosf(-TWO_PI * (float)kc * invl, &sim, &sre);

    float ar[2][4] = {}, ai[2][4] = {};

    for (int t0 = 0; t0 < l; t0 += 64) {
        const int tt = min(64, l - t0);
        __syncthreads();
        for (int p = tid; p < tt * 32; p += 256) {
            const int row = p >> 5, c4 = (p & 31) << 2;
            *(float4*)&xs[row][c4] =
                *(const float4*)&x[((size_t)b * SL + (size_t)(t0 + row)) * ND + c4];
        }
        __syncthreads();

        // exact re-seed at chunk start: idx0 = (k*t0) mod l
        const int idx0 = (kc * t0) % l;
        float cim, cre;
        sincosf(-TWO_PI * (float)idx0 * invl, &cim, &cre);

#pragma unroll 4
        for (int t = 0; t < tt; ++t) {
            const float4 xa = *(const float4*)&xs[t][d0a];
            const float4 xb = *(const float4*)&xs[t][d0b];
            ar[0][0] = fmaf(cre, xa.x, ar[0][0]); ai[0][0] = fmaf(cim, xa.x, ai[0][0]);
            ar[0][1] = fmaf(cre, xa.y, ar[0][1]); ai[0][1] = fmaf(cim, xa.y, ai[0][1]);
            ar[0][2] = fmaf(cre, xa.z, ar[0][2]); ai[0][2] = fmaf(cim, xa.z, ai[0][2]);
            ar[0][3] = fmaf(cre, xa.w, ar[0][3]); ai[0][3] = fmaf(cim, xa.w, ai[0][3]);
            ar[1][0] = fmaf(cre, xb.x, ar[1][0]); ai[1][0] = fmaf(cim, xb.x, ai[1][0]);
            ar[1][1] = fmaf(cre, xb.y, ar[1][1]); ai[1][1] = fmaf(cim, xb.y, ai[1][1]);
            ar[1][2] = fmaf(cre, xb.z, ar[1][2]); ai[1][2] = fmaf(cim, xb.z, ai[1][2]);
            ar[1][3] = fmaf(cre, xb.w, ar[1][3]); ai[1][3] = fmaf(cim, xb.w, ai[1][3]);
            // cur *= step
            const float ncr = fmaf(cre, sre, -cim * sim);
            const float nci = fmaf(cre, sim, cim * sre);
            cre = ncr; cim = nci;
        }
    }

    if (!act) return;
    const int d0s[2] = {d0a, d0b};
#pragma unroll
    for (int q = 0; q < 2; ++q) {
        const float4 sc = *(const float4*)&ws_ro[SCALE_OFF + b * ND + d0s[q]];
        const float4 bi = *(const float4*)&ws_ro[BIAS_OFF + b * ND + d0s[q]];
        const size_t o = (size_t)b * SL * ND + (size_t)k * ND + d0s[q];
        const float4 fr = make_float4(fmaf(ar[q][0], sc.x, bi.x), fmaf(ar[q][1], sc.y, bi.y),
                                      fmaf(ar[q][2], sc.z, bi.z), fmaf(ar[q][3], sc.w, bi.w));
        const float4 fi = make_float4(ai[q][0] * sc.x, ai[q][1] * sc.y,
                                      ai[q][2] * sc.z, ai[q][3] * sc.w);
        *(float4*)&ws[FILTR_OFF + o] = fr;
        *(float4*)&ws[FILTI_OFF + o] = fi;
    }
}

// ---------------- K4: inverse DFT, real part only ----------------
__global__ __launch_bounds__(256) void k_inv(const float* __restrict__ ws,
                                             const int* __restrict__ len_x,
                                             float* __restrict__ out) {
    const int b = blockIdx.x >> 6;
    const int ktile = blockIdx.x & 63;
    const int l = len_x[b];
    const int kbase = ktile * 16;
    if (kbase >= l) return;

    const int tid = threadIdx.x;
    const int kq = tid >> 4;
    const int dq = tid & 15;
    const int k = kbase + kq;
    const bool act = (k < l);
    const int kc = act ? k : 0;
    const int d0a = dq * 4, d0b = 64 + dq * 4;
    const float invl = 1.f / (float)l;

    __shared__ float fsr[32][ND];
    __shared__ float fsi[32][ND];

    float sim, sre;
    sincosf(TWO_PI * (float)kc * invl, &sim, &sre);

    float ar[2][4] = {};

    for (int t0 = 0; t0 < l; t0 += 32) {
        const int tt = min(32, l - t0);
        __syncthreads();
        for (int p = tid; p < tt * 32; p += 256) {
            const int row = p >> 5, c4 = (p & 31) << 2;
            const size_t o = (size_t)b * SL * ND + (size_t)(t0 + row) * ND + c4;
            *(float4*)&fsr[row][c4] = *(const float4*)&ws[FILTR_OFF + o];
            *(float4*)&fsi[row][c4] = *(const float4*)&ws[FILTI_OFF + o];
        }
        __syncthreads();

        const int idx0 = (kc * t0) % l;
        float cim, cre;
        sincosf(TWO_PI * (float)idx0 * invl, &cim, &cre);

#pragma unroll 4
        for (int t = 0; t < tt; ++t) {
            const float4 ra = *(const float4*)&fsr[t][d0a];
            const float4 ia = *(const float4*)&fsi[t][d0a];
            const float4 rb = *(const float4*)&fsr[t][d0b];
            const float4 ib = *(const float4*)&fsi[t][d0b];
            ar[0][0] = fmaf(cre, ra.x, fmaf(-cim, ia.x, ar[0][0]));
            ar[0][1] = fmaf(cre, ra.y, fmaf(-cim, ia.y, ar[0][1]));
            ar[0][2] = fmaf(cre, ra.z, fmaf(-cim, ia.z, ar[0][2]));
            ar[0][3] = fmaf(cre, ra.w, fmaf(-cim, ia.w, ar[0][3]));
            ar[1][0] = fmaf(cre, rb.x, fmaf(-cim, ib.x, ar[1][0]));
            ar[1][1] = fmaf(cre, rb.y, fmaf(-cim, ib.y, ar[1][1]));
            ar[1][2] = fmaf(cre, rb.z, fmaf(-cim, ib.z, ar[1][2]));
            ar[1][3] = fmaf(cre, rb.w, fmaf(-cim, ib.w, ar[1][3]));
            const float ncr = fmaf(cre, sre, -cim * sim);
            const float nci = fmaf(cre, sim, cim * sre);
            cre = ncr; cim = nci;
        }
    }

    if (!act) return;
    const int d0s[2] = {d0a, d0b};
#pragma unroll
    for (int q = 0; q < 2; ++q) {
        const float4 v = make_float4(ar[q][0] * invl, ar[q][1] * invl,
                                     ar[q][2] * invl, ar[q][3] * invl);
        *(float4*)&out[((size_t)b * SL + (size_t)k) * ND + d0s[q]] = v;
    }
}

extern "C" void kernel_launch(void* const* d_in, const int* in_sizes, int n_in,
                              void* d_out, int out_size, void* d_ws, size_t ws_size,
                              hipStream_t stream) {
    const float* x = (const float*)d_in[0];
    const float* y = (const float*)d_in[1];
    const float* z = (const float*)d_in[2];
    const int* len_x = (const int*)d_in[3];
    const int* len_y = (const int*)d_in[4];
    const int* len_z = (const int*)d_in[5];
    float* ws = (float*)d_ws;
    float* out = (float*)d_out;

    k_partial<<<2 * NB * 8, 256, 0, stream>>>(y, z, ws);

    k_mlp<<<NB, 256, 0, stream>>>(ws, len_y, len_z,
        (const float*)d_in[6],  (const float*)d_in[7],  (const float*)d_in[8],  (const float*)d_in[9],
        (const float*)d_in[10], (const float*)d_in[11], (const float*)d_in[12], (const float*)d_in[13],
        (const float*)d_in[14], (const float*)d_in[15], (const float*)d_in[16], (const float*)d_in[17],
        (const float*)d_in[18], (const float*)d_in[19], (const float*)d_in[20], (const float*)d_in[21]);

    k_fwd<<<NB * 64, 256, 0, stream>>>(x, len_x, ws, ws);

    hipMemsetAsync(d_out, 0, (size_t)NB * SL * ND * sizeof(float), stream);

    k_inv<<<NB * 64, 256, 0, stream>>>(ws, len_x, out);
}

// Round 3
// 225.377 us; speedup vs baseline: 1.5400x; 1.2983x over previous
//
#include <hip/hip_runtime.h>
#include <math.h>

constexpr int NB = 16;    // batch
constexpr int SL = 1024;  // L
constexpr int ND = 128;   // D
constexpr int NH = 256;   // H

// ws layout (float indices)
constexpr int P_OFF     = 0;                        // [2][NB][8][ND] partial sums
constexpr int SCALE_OFF = 2 * NB * 8 * ND;          // [NB][ND]
constexpr int BIAS_OFF  = SCALE_OFF + NB * ND;      // [NB][ND]
constexpr int FILTR_OFF = BIAS_OFF + NB * ND;       // [NB][SL][ND] real plane (weighted)
constexpr int FILTI_OFF = FILTR_OFF + NB * SL * ND; // [NB][SL][ND] imag plane (weighted)

constexpr float TWO_PI = 6.283185307179586f;

// ---------------- K1: partial sums of y and z over t ----------------
__global__ __launch_bounds__(256) void k_partial(const float* __restrict__ y,
                                                 const float* __restrict__ z,
                                                 float* __restrict__ ws) {
    const int blk = blockIdx.x;
    const int ch  = blk & 7;
    const int b   = (blk >> 3) & 15;
    const int src = blk >> 7;
    const float* base = (src == 0 ? y : z) + (size_t)b * SL * ND;
    const int d    = threadIdx.x & 127;
    const int half = threadIdx.x >> 7;
    float s = 0.f;
    const int t0 = ch * 128 + half;
    for (int t = 0; t < 128; t += 2)
        s += base[(size_t)(t0 + t) * ND + d];
    __shared__ float red[256];
    red[threadIdx.x] = s;
    __syncthreads();
    if (half == 0)
        ws[P_OFF + ((size_t)(src * NB + b) * 8 + ch) * ND + d] = s + red[d + 128];
}

// ---------------- K2: MLPs -> scale/bias ----------------
__global__ __launch_bounds__(256) void k_mlp(
    float* __restrict__ ws,
    const int* __restrict__ len_y, const int* __restrict__ len_z,
    const float* __restrict__ W1w1, const float* __restrict__ W1b1,
    const float* __restrict__ W1w2, const float* __restrict__ W1b2,
    const float* __restrict__ B1w1, const float* __restrict__ B1b1,
    const float* __restrict__ B1w2, const float* __restrict__ B1b2,
    const float* __restrict__ W2w1, const float* __restrict__ W2b1,
    const float* __restrict__ W2w2, const float* __restrict__ W2b2,
    const float* __restrict__ B2w1, const float* __restrict__ B2b1,
    const float* __restrict__ B2w2, const float* __restrict__ B2b2) {
    const int b = blockIdx.x;
    const int tid = threadIdx.x;
    __shared__ float c1[ND], c2[ND];
    __shared__ float h[4][NH];
    __shared__ float o[4][ND];

    if (tid < ND) {
        float s = 0.f;
        for (int ch = 0; ch < 8; ++ch)
            s += ws[P_OFF + ((size_t)(0 * NB + b) * 8 + ch) * ND + tid];
        c1[tid] = s / (float)len_y[b];
    } else {
        const int d = tid - ND;
        float s = 0.f;
        for (int ch = 0; ch < 8; ++ch)
            s += ws[P_OFF + ((size_t)(1 * NB + b) * 8 + ch) * ND + d];
        c2[d] = s / (float)len_z[b];
    }
    __syncthreads();

    const float* w1s[4] = {W1w1, B1w1, W2w1, B2w1};
    const float* b1s[4] = {W1b1, B1b1, W2b1, B2b1};
    const float* w2s[4] = {W1w2, B1w2, W2w2, B2w2};
    const float* b2s[4] = {W1b2, B1b2, W2b2, B2b2};

    for (int m = 0; m < 4; ++m) {
        const float* c = (m < 2) ? c1 : c2;
        const float* w = w1s[m];
        const int j = tid;
        float s = b1s[m][j];
        for (int i = 0; i < ND; ++i)
            s = fmaf(c[i], w[i * NH + j], s);
        h[m][j] = 0.5f * s * (1.f + erff(s * 0.7071067811865475f));
    }
    __syncthreads();

    for (int p = tid; p < 4 * ND; p += 256) {
        const int m = p >> 7, d = p & 127;
        const float* w = w2s[m];
        float s = b2s[m][d];
        for (int j = 0; j < NH; ++j)
            s = fmaf(h[m][j], w[j * ND + d], s);
        o[m][d] = s;
    }
    __syncthreads();

    if (tid < ND) {
        ws[SCALE_OFF + b * ND + tid] = 1.f + 0.5f * (o[0][tid] + o[2][tid]);
        ws[BIAS_OFF  + b * ND + tid] = 0.5f * (o[1][tid] + o[3][tid]);
    }
}

// ---------------- K3: forward DFT (rows k=0..l/2) + real filter + weight ----------------
// grid: (17, NB). Block tile: 32 k-rows x 128 d. Thread: 2 k-rows x 8 d.
__global__ __launch_bounds__(256) void k_fwd(const float* __restrict__ x,
                                             const int* __restrict__ len_x,
                                             const float* __restrict__ ws_ro,
                                             float* __restrict__ ws) {
    const int b = blockIdx.y;
    const int l = len_x[b];
    const int KH = l >> 1;               // last stored row
    const int kbase = blockIdx.x * 32;
    if (kbase > KH) return;

    const int tid = threadIdx.x;
    const int rq = tid >> 4;             // 0..15
    const int dq = tid & 15;
    const int d0a = dq * 4, d0b = 64 + dq * 4;
    const float invl = 1.f / (float)l;

    int kk[2]; bool act[2];
    float sre[2], sim[2];
#pragma unroll
    for (int i = 0; i < 2; ++i) {
        const int k = kbase + rq + 16 * i;
        act[i] = (k <= KH);
        kk[i] = act[i] ? k : 0;
        sincosf(-TWO_PI * (float)kk[i] * invl, &sim[i], &sre[i]);
    }

    float ar[2][8] = {}, ai[2][8] = {};
    __shared__ float xs[64][ND];

    for (int t0 = 0; t0 < l; t0 += 64) {
        const int tt = min(64, l - t0);
        __syncthreads();
        for (int p = tid; p < tt * 32; p += 256) {
            const int row = p >> 5, c4 = (p & 31) << 2;
            *(float4*)&xs[row][c4] =
                *(const float4*)&x[((size_t)b * SL + (size_t)(t0 + row)) * ND + c4];
        }
        __syncthreads();

        float cre[2], cim[2];
#pragma unroll
        for (int i = 0; i < 2; ++i) {
            const int idx0 = (kk[i] * t0) % l;
            sincosf(-TWO_PI * (float)idx0 * invl, &cim[i], &cre[i]);
        }

#pragma unroll 4
        for (int t = 0; t < tt; ++t) {
            const float4 xa = *(const float4*)&xs[t][d0a];
            const float4 xb = *(const float4*)&xs[t][d0b];
#pragma unroll
            for (int i = 0; i < 2; ++i) {
                const float cr = cre[i], ci = cim[i];
                ar[i][0] = fmaf(cr, xa.x, ar[i][0]); ai[i][0] = fmaf(ci, xa.x, ai[i][0]);
                ar[i][1] = fmaf(cr, xa.y, ar[i][1]); ai[i][1] = fmaf(ci, xa.y, ai[i][1]);
                ar[i][2] = fmaf(cr, xa.z, ar[i][2]); ai[i][2] = fmaf(ci, xa.z, ai[i][2]);
                ar[i][3] = fmaf(cr, xa.w, ar[i][3]); ai[i][3] = fmaf(ci, xa.w, ai[i][3]);
                ar[i][4] = fmaf(cr, xb.x, ar[i][4]); ai[i][4] = fmaf(ci, xb.x, ai[i][4]);
                ar[i][5] = fmaf(cr, xb.y, ar[i][5]); ai[i][5] = fmaf(ci, xb.y, ai[i][5]);
                ar[i][6] = fmaf(cr, xb.z, ar[i][6]); ai[i][6] = fmaf(ci, xb.z, ai[i][6]);
                ar[i][7] = fmaf(cr, xb.w, ar[i][7]); ai[i][7] = fmaf(ci, xb.w, ai[i][7]);
                cre[i] = fmaf(cr, sre[i], -ci * sim[i]);
                cim[i] = fmaf(cr, sim[i], ci * sre[i]);
            }
        }
    }

#pragma unroll
    for (int i = 0; i < 2; ++i) {
        if (!act[i]) continue;
        const float w = (kk[i] == 0 || 2 * kk[i] == l) ? 1.f : 2.f;
        const int d0s[2] = {d0a, d0b};
#pragma unroll
        for (int q = 0; q < 2; ++q) {
            const float4 sc = *(const float4*)&ws_ro[SCALE_OFF + b * ND + d0s[q]];
            const float4 bi = *(const float4*)&ws_ro[BIAS_OFF + b * ND + d0s[q]];
            const size_t o = (size_t)b * SL * ND + (size_t)kk[i] * ND + d0s[q];
            const float4 fr = make_float4(w * fmaf(ar[i][4 * q + 0], sc.x, bi.x),
                                          w * fmaf(ar[i][4 * q + 1], sc.y, bi.y),
                                          w * fmaf(ar[i][4 * q + 2], sc.z, bi.z),
                                          w * fmaf(ar[i][4 * q + 3], sc.w, bi.w));
            const float4 fi = make_float4(w * ai[i][4 * q + 0] * sc.x,
                                          w * ai[i][4 * q + 1] * sc.y,
                                          w * ai[i][4 * q + 2] * sc.z,
                                          w * ai[i][4 * q + 3] * sc.w);
            *(float4*)&ws[FILTR_OFF + o] = fr;
            *(float4*)&ws[FILTI_OFF + o] = fi;
        }
    }
}

// ---------------- K4: inverse DFT, real output, k-sum over half spectrum ----------------
// grid: (32, NB). Block tile: 32 t-rows x 128 d. Thread: 2 t-rows x 8 d.
// out[t,d] = invl * sum_{k=0}^{KH} ( Fr'[k,d]*cos(2pi k t/l) - Fi'[k,d]*sin(2pi k t/l) )
__global__ __launch_bounds__(256) void k_inv(const float* __restrict__ ws,
                                             const int* __restrict__ len_x,
                                             float* __restrict__ out) {
    const int b = blockIdx.y;
    const int l = len_x[b];
    const int KH = l >> 1;
    const int tbase = blockIdx.x * 32;
    if (tbase >= l) return;

    const int tid = threadIdx.x;
    const int rq = tid >> 4;
    const int dq = tid & 15;
    const int d0a = dq * 4, d0b = 64 + dq * 4;
    const float invl = 1.f / (float)l;

    int ttr[2]; bool act[2];
    float sre[2], sim[2];
#pragma unroll
    for (int i = 0; i < 2; ++i) {
        const int t = tbase + rq + 16 * i;
        act[i] = (t < l);
        ttr[i] = act[i] ? t : 0;
        sincosf(TWO_PI * (float)ttr[i] * invl, &sim[i], &sre[i]);
    }

    float ar[2][8] = {};
    __shared__ float fsr[32][ND];
    __shared__ float fsi[32][ND];

    for (int k0 = 0; k0 <= KH; k0 += 32) {
        const int kn = min(32, KH + 1 - k0);
        __syncthreads();
        for (int p = tid; p < kn * 32; p += 256) {
            const int row = p >> 5, c4 = (p & 31) << 2;
            const size_t o = (size_t)b * SL * ND + (size_t)(k0 + row) * ND + c4;
            *(float4*)&fsr[row][c4] = *(const float4*)&ws[FILTR_OFF + o];
            *(float4*)&fsi[row][c4] = *(const float4*)&ws[FILTI_OFF + o];
        }
        __syncthreads();

        float cre[2], cim[2];
#pragma unroll
        for (int i = 0; i < 2; ++i) {
            const int idx0 = (ttr[i] * k0) % l;
            sincosf(TWO_PI * (float)idx0 * invl, &cim[i], &cre[i]);
        }

#pragma unroll 4
        for (int k = 0; k < kn; ++k) {
            const float4 ra = *(const float4*)&fsr[k][d0a];
            const float4 ia = *(const float4*)&fsi[k][d0a];
            const float4 rb = *(const float4*)&fsr[k][d0b];
            const float4 ib = *(const float4*)&fsi[k][d0b];
#pragma unroll
            for (int i = 0; i < 2; ++i) {
                const float cr = cre[i], ci = cim[i];
                ar[i][0] = fmaf(cr, ra.x, fmaf(-ci, ia.x, ar[i][0]));
                ar[i][1] = fmaf(cr, ra.y, fmaf(-ci, ia.y, ar[i][1]));
                ar[i][2] = fmaf(cr, ra.z, fmaf(-ci, ia.z, ar[i][2]));
                ar[i][3] = fmaf(cr, ra.w, fmaf(-ci, ia.w, ar[i][3]));
                ar[i][4] = fmaf(cr, rb.x, fmaf(-ci, ib.x, ar[i][4]));
                ar[i][5] = fmaf(cr, rb.y, fmaf(-ci, ib.y, ar[i][5]));
                ar[i][6] = fmaf(cr, rb.z, fmaf(-ci, ib.z, ar[i][6]));
                ar[i][7] = fmaf(cr, rb.w, fmaf(-ci, ib.w, ar[i][7]));
                cre[i] = fmaf(cr, sre[i], -ci * sim[i]);
                cim[i] = fmaf(cr, sim[i], ci * sre[i]);
            }
        }
    }

#pragma unroll
    for (int i = 0; i < 2; ++i) {
        if (!act[i]) continue;
        const float4 va = make_float4(ar[i][0] * invl, ar[i][1] * invl,
                                      ar[i][2] * invl, ar[i][3] * invl);
        const float4 vb = make_float4(ar[i][4] * invl, ar[i][5] * invl,
                                      ar[i][6] * invl, ar[i][7] * invl);
        *(float4*)&out[((size_t)b * SL + (size_t)ttr[i]) * ND + d0a] = va;
        *(float4*)&out[((size_t)b * SL + (size_t)ttr[i]) * ND + d0b] = vb;
    }
}

extern "C" void kernel_launch(void* const* d_in, const int* in_sizes, int n_in,
                              void* d_out, int out_size, void* d_ws, size_t ws_size,
                              hipStream_t stream) {
    const float* x = (const float*)d_in[0];
    const float* y = (const float*)d_in[1];
    const float* z = (const float*)d_in[2];
    const int* len_x = (const int*)d_in[3];
    const int* len_y = (const int*)d_in[4];
    const int* len_z = (const int*)d_in[5];
    float* ws = (float*)d_ws;
    float* out = (float*)d_out;

    k_partial<<<2 * NB * 8, 256, 0, stream>>>(y, z, ws);

    k_mlp<<<NB, 256, 0, stream>>>(ws, len_y, len_z,
        (const float*)d_in[6],  (const float*)d_in[7],  (const float*)d_in[8],  (const float*)d_in[9],
        (const float*)d_in[10], (const float*)d_in[11], (const float*)d_in[12], (const float*)d_in[13],
        (const float*)d_in[14], (const float*)d_in[15], (const float*)d_in[16], (const float*)d_in[17],
        (const float*)d_in[18], (const float*)d_in[19], (const float*)d_in[20], (const float*)d_in[21]);

    k_fwd<<<dim3(17, NB), 256, 0, stream>>>(x, len_x, ws, ws);

    hipMemsetAsync(d_out, 0, (size_t)NB * SL * ND * sizeof(float), stream);

    k_inv<<<dim3(32, NB), 256, 0, stream>>>(ws, len_x, out);
}

// Round 4
// 188.941 us; speedup vs baseline: 1.8370x; 1.1928x over previous
//
#include <hip/hip_runtime.h>
#include <math.h>

constexpr int NB = 16;    // batch
constexpr int SL = 1024;  // L
constexpr int ND = 128;   // D
constexpr int NH = 256;   // H

// ws layout (float indices)
constexpr int P_OFF     = 0;                        // [2][NB][8][ND] partial sums
constexpr int SCALE_OFF = 2 * NB * 8 * ND;          // [NB][ND]
constexpr int BIAS_OFF  = SCALE_OFF + NB * ND;      // [NB][ND]
constexpr int FILTR_OFF = BIAS_OFF + NB * ND;       // [NB][SL][ND] real plane (weighted)
constexpr int FILTI_OFF = FILTR_OFF + NB * SL * ND; // [NB][SL][ND] imag plane (weighted)

constexpr float TWO_PI = 6.283185307179586f;

// ---------------- K1: partial sums of y and z over t ----------------
__global__ __launch_bounds__(256) void k_partial(const float* __restrict__ y,
                                                 const float* __restrict__ z,
                                                 float* __restrict__ ws) {
    const int blk = blockIdx.x;
    const int ch  = blk & 7;
    const int b   = (blk >> 3) & 15;
    const int src = blk >> 7;
    const float* base = (src == 0 ? y : z) + (size_t)b * SL * ND;
    const int d    = threadIdx.x & 127;
    const int half = threadIdx.x >> 7;
    float s = 0.f;
    const int t0 = ch * 128 + half;
    for (int t = 0; t < 128; t += 2)
        s += base[(size_t)(t0 + t) * ND + d];
    __shared__ float red[256];
    red[threadIdx.x] = s;
    __syncthreads();
    if (half == 0)
        ws[P_OFF + ((size_t)(src * NB + b) * 8 + ch) * ND + d] = s + red[d + 128];
}

// ---------------- K2: MLPs -> scale/bias ----------------
__global__ __launch_bounds__(256) void k_mlp(
    float* __restrict__ ws,
    const int* __restrict__ len_y, const int* __restrict__ len_z,
    const float* __restrict__ W1w1, const float* __restrict__ W1b1,
    const float* __restrict__ W1w2, const float* __restrict__ W1b2,
    const float* __restrict__ B1w1, const float* __restrict__ B1b1,
    const float* __restrict__ B1w2, const float* __restrict__ B1b2,
    const float* __restrict__ W2w1, const float* __restrict__ W2b1,
    const float* __restrict__ W2w2, const float* __restrict__ W2b2,
    const float* __restrict__ B2w1, const float* __restrict__ B2b1,
    const float* __restrict__ B2w2, const float* __restrict__ B2b2) {
    const int b = blockIdx.x;
    const int tid = threadIdx.x;
    __shared__ float c1[ND], c2[ND];
    __shared__ float h[4][NH];
    __shared__ float o[4][ND];

    if (tid < ND) {
        float s = 0.f;
        for (int ch = 0; ch < 8; ++ch)
            s += ws[P_OFF + ((size_t)(0 * NB + b) * 8 + ch) * ND + tid];
        c1[tid] = s / (float)len_y[b];
    } else {
        const int d = tid - ND;
        float s = 0.f;
        for (int ch = 0; ch < 8; ++ch)
            s += ws[P_OFF + ((size_t)(1 * NB + b) * 8 + ch) * ND + d];
        c2[d] = s / (float)len_z[b];
    }
    __syncthreads();

    const float* w1s[4] = {W1w1, B1w1, W2w1, B2w1};
    const float* b1s[4] = {W1b1, B1b1, W2b1, B2b1};
    const float* w2s[4] = {W1w2, B1w2, W2w2, B2w2};
    const float* b2s[4] = {W1b2, B1b2, W2b2, B2b2};

    for (int m = 0; m < 4; ++m) {
        const float* c = (m < 2) ? c1 : c2;
        const float* w = w1s[m];
        const int j = tid;
        float s = b1s[m][j];
        for (int i = 0; i < ND; ++i)
            s = fmaf(c[i], w[i * NH + j], s);
        h[m][j] = 0.5f * s * (1.f + erff(s * 0.7071067811865475f));
    }
    __syncthreads();

    for (int p = tid; p < 4 * ND; p += 256) {
        const int m = p >> 7, d = p & 127;
        const float* w = w2s[m];
        float s = b2s[m][d];
        for (int j = 0; j < NH; ++j)
            s = fmaf(h[m][j], w[j * ND + d], s);
        o[m][d] = s;
    }
    __syncthreads();

    if (tid < ND) {
        ws[SCALE_OFF + b * ND + tid] = 1.f + 0.5f * (o[0][tid] + o[2][tid]);
        ws[BIAS_OFF  + b * ND + tid] = 0.5f * (o[1][tid] + o[3][tid]);
    }
}

// ---------------- K3: forward DFT (rows k=0..l/2) + real filter + weight ----------------
// grid: (17 ktiles, 4 dquads, NB). Block tile: 32 k-rows x 32 d.
// Thread (256 = 32 rq x 8 dq): 1 k-row x 4 d.
__global__ __launch_bounds__(256) void k_fwd(const float* __restrict__ x,
                                             const int* __restrict__ len_x,
                                             const float* __restrict__ ws_ro,
                                             float* __restrict__ ws) {
    const int b = blockIdx.z;
    const int l = len_x[b];
    const int KH = l >> 1;               // last stored row
    const int kbase = blockIdx.x * 32;
    if (kbase > KH) return;
    const int dbase = blockIdx.y * 32;

    const int tid = threadIdx.x;
    const int rq = tid >> 3;             // 0..31 : k-row within tile
    const int dq = tid & 7;              // 0..7  : d-quad within 32-d slice
    const int d0 = dbase + dq * 4;
    const float invl = 1.f / (float)l;

    const int k = kbase + rq;
    const bool act = (k <= KH);
    const int kc = act ? k : 0;
    float sre, sim;
    sincosf(-TWO_PI * (float)kc * invl, &sim, &sre);

    float ar[4] = {}, ai[4] = {};
    __shared__ float xs[64][32];

    for (int t0 = 0; t0 < l; t0 += 64) {
        const int tt = min(64, l - t0);
        __syncthreads();
        for (int p = tid; p < tt * 8; p += 256) {
            const int row = p >> 3, c4 = (p & 7) << 2;
            *(float4*)&xs[row][c4] =
                *(const float4*)&x[((size_t)b * SL + (size_t)(t0 + row)) * ND + dbase + c4];
        }
        __syncthreads();

        const int idx0 = (kc * t0) % l;
        float cre, cim;
        sincosf(-TWO_PI * (float)idx0 * invl, &cim, &cre);

#pragma unroll 4
        for (int t = 0; t < tt; ++t) {
            const float4 xa = *(const float4*)&xs[t][dq * 4];
            ar[0] = fmaf(cre, xa.x, ar[0]); ai[0] = fmaf(cim, xa.x, ai[0]);
            ar[1] = fmaf(cre, xa.y, ar[1]); ai[1] = fmaf(cim, xa.y, ai[1]);
            ar[2] = fmaf(cre, xa.z, ar[2]); ai[2] = fmaf(cim, xa.z, ai[2]);
            ar[3] = fmaf(cre, xa.w, ar[3]); ai[3] = fmaf(cim, xa.w, ai[3]);
            const float ncr = fmaf(cre, sre, -cim * sim);
            const float nci = fmaf(cre, sim, cim * sre);
            cre = ncr; cim = nci;
        }
    }

    if (!act) return;
    const float w = (kc == 0 || 2 * kc == l) ? 1.f : 2.f;
    const float4 sc = *(const float4*)&ws_ro[SCALE_OFF + b * ND + d0];
    const float4 bi = *(const float4*)&ws_ro[BIAS_OFF + b * ND + d0];
    const size_t o = (size_t)b * SL * ND + (size_t)kc * ND + d0;
    const float4 fr = make_float4(w * fmaf(ar[0], sc.x, bi.x), w * fmaf(ar[1], sc.y, bi.y),
                                  w * fmaf(ar[2], sc.z, bi.z), w * fmaf(ar[3], sc.w, bi.w));
    const float4 fi = make_float4(w * ai[0] * sc.x, w * ai[1] * sc.y,
                                  w * ai[2] * sc.z, w * ai[3] * sc.w);
    *(float4*)&ws[FILTR_OFF + o] = fr;
    *(float4*)&ws[FILTI_OFF + o] = fi;
}

// ---------------- K4: inverse DFT, real output, k-sum over half spectrum ----------------
// grid: (32 ttiles, 4 dquads, NB). Block tile: 32 t-rows x 32 d.
// Thread (256 = 32 rq x 8 dq): 1 t-row x 4 d.
// out[t,d] = invl * sum_{k=0}^{KH} ( Fr'[k,d]*cos(2pi k t/l) - Fi'[k,d]*sin(2pi k t/l) )
__global__ __launch_bounds__(256) void k_inv(const float* __restrict__ ws,
                                             const int* __restrict__ len_x,
                                             float* __restrict__ out) {
    const int b = blockIdx.z;
    const int l = len_x[b];
    const int KH = l >> 1;
    const int tbase = blockIdx.x * 32;
    if (tbase >= l) return;
    const int dbase = blockIdx.y * 32;

    const int tid = threadIdx.x;
    const int rq = tid >> 3;
    const int dq = tid & 7;
    const int d0 = dbase + dq * 4;
    const float invl = 1.f / (float)l;

    const int t = tbase + rq;
    const bool act = (t < l);
    const int tc = act ? t : 0;
    float sre, sim;
    sincosf(TWO_PI * (float)tc * invl, &sim, &sre);

    float ar[4] = {};
    __shared__ float fsr[32][32];
    __shared__ float fsi[32][32];

    for (int k0 = 0; k0 <= KH; k0 += 32) {
        const int kn = min(32, KH + 1 - k0);
        __syncthreads();
        for (int p = tid; p < kn * 8; p += 256) {
            const int row = p >> 3, c4 = (p & 7) << 2;
            const size_t o = (size_t)b * SL * ND + (size_t)(k0 + row) * ND + dbase + c4;
            *(float4*)&fsr[row][c4] = *(const float4*)&ws[FILTR_OFF + o];
            *(float4*)&fsi[row][c4] = *(const float4*)&ws[FILTI_OFF + o];
        }
        __syncthreads();

        const int idx0 = (tc * k0) % l;
        float cre, cim;
        sincosf(TWO_PI * (float)idx0 * invl, &cim, &cre);

#pragma unroll 4
        for (int kk = 0; kk < kn; ++kk) {
            const float4 ra = *(const float4*)&fsr[kk][dq * 4];
            const float4 ia = *(const float4*)&fsi[kk][dq * 4];
            ar[0] = fmaf(cre, ra.x, fmaf(-cim, ia.x, ar[0]));
            ar[1] = fmaf(cre, ra.y, fmaf(-cim, ia.y, ar[1]));
            ar[2] = fmaf(cre, ra.z, fmaf(-cim, ia.z, ar[2]));
            ar[3] = fmaf(cre, ra.w, fmaf(-cim, ia.w, ar[3]));
            const float ncr = fmaf(cre, sre, -cim * sim);
            const float nci = fmaf(cre, sim, cim * sre);
            cre = ncr; cim = nci;
        }
    }

    if (!act) return;
    const float4 v = make_float4(ar[0] * invl, ar[1] * invl, ar[2] * invl, ar[3] * invl);
    *(float4*)&out[((size_t)b * SL + (size_t)tc) * ND + d0] = v;
}

extern "C" void kernel_launch(void* const* d_in, const int* in_sizes, int n_in,
                              void* d_out, int out_size, void* d_ws, size_t ws_size,
                              hipStream_t stream) {
    const float* x = (const float*)d_in[0];
    const float* y = (const float*)d_in[1];
    const float* z = (const float*)d_in[2];
    const int* len_x = (const int*)d_in[3];
    const int* len_y = (const int*)d_in[4];
    const int* len_z = (const int*)d_in[5];
    float* ws = (float*)d_ws;
    float* out = (float*)d_out;

    hipMemsetAsync(d_out, 0, (size_t)NB * SL * ND * sizeof(float), stream);

    k_partial<<<2 * NB * 8, 256, 0, stream>>>(y, z, ws);

    k_mlp<<<NB, 256, 0, stream>>>(ws, len_y, len_z,
        (const float*)d_in[6],  (const float*)d_in[7],  (const float*)d_in[8],  (const float*)d_in[9],
        (const float*)d_in[10], (const float*)d_in[11], (const float*)d_in[12], (const float*)d_in[13],
        (const float*)d_in[14], (const float*)d_in[15], (const float*)d_in[16], (const float*)d_in[17],
        (const float*)d_in[18], (const float*)d_in[19], (const float*)d_in[20], (const float*)d_in[21]);

    k_fwd<<<dim3(17, 4, NB), 256, 0, stream>>>(x, len_x, ws, ws);

    k_inv<<<dim3(32, 4, NB), 256, 0, stream>>>(ws, len_x, out);
}

// Round 5
// 137.963 us; speedup vs baseline: 2.5158x; 1.3695x over previous
//
#include <hip/hip_runtime.h>
#include <math.h>

constexpr int NB = 16;    // batch
constexpr int SL = 1024;  // L
constexpr int ND = 128;   // D
constexpr int NH = 256;   // H

// ws layout (float indices)
constexpr int P_OFF     = 0;                        // [2][NB][8][ND] partial sums
constexpr int SCALE_OFF = 2 * NB * 8 * ND;          // [NB][ND]
constexpr int BIAS_OFF  = SCALE_OFF + NB * ND;      // [NB][ND]
constexpr int FILTR_OFF = BIAS_OFF + NB * ND;       // [NB][SL][ND] real plane (weighted)
constexpr int FILTI_OFF = FILTR_OFF + NB * SL * ND; // [NB][SL][ND] imag plane (weighted)

constexpr float TWO_PI = 6.283185307179586f;

// ---------------- K1: partial sums of y and z over t ----------------
__global__ __launch_bounds__(256) void k_partial(const float* __restrict__ y,
                                                 const float* __restrict__ z,
                                                 float* __restrict__ ws) {
    const int blk = blockIdx.x;
    const int ch  = blk & 7;
    const int b   = (blk >> 3) & 15;
    const int src = blk >> 7;
    const float* base = (src == 0 ? y : z) + (size_t)b * SL * ND;
    const int d    = threadIdx.x & 127;
    const int half = threadIdx.x >> 7;
    float s = 0.f;
    const int t0 = ch * 128 + half;
    for (int t = 0; t < 128; t += 2)
        s += base[(size_t)(t0 + t) * ND + d];
    __shared__ float red[256];
    red[threadIdx.x] = s;
    __syncthreads();
    if (half == 0)
        ws[P_OFF + ((size_t)(src * NB + b) * 8 + ch) * ND + d] = s + red[d + 128];
}

// ---------------- K2: MLPs -> scale/bias ----------------
__global__ __launch_bounds__(256) void k_mlp(
    float* __restrict__ ws,
    const int* __restrict__ len_y, const int* __restrict__ len_z,
    const float* __restrict__ W1w1, const float* __restrict__ W1b1,
    const float* __restrict__ W1w2, const float* __restrict__ W1b2,
    const float* __restrict__ B1w1, const float* __restrict__ B1b1,
    const float* __restrict__ B1w2, const float* __restrict__ B1b2,
    const float* __restrict__ W2w1, const float* __restrict__ W2b1,
    const float* __restrict__ W2w2, const float* __restrict__ W2b2,
    const float* __restrict__ B2w1, const float* __restrict__ B2b1,
    const float* __restrict__ B2w2, const float* __restrict__ B2b2) {
    const int b = blockIdx.x;
    const int tid = threadIdx.x;
    __shared__ float c1[ND], c2[ND];
    __shared__ float h[4][NH];
    __shared__ float o[4][ND];

    if (tid < ND) {
        float s = 0.f;
        for (int ch = 0; ch < 8; ++ch)
            s += ws[P_OFF + ((size_t)(0 * NB + b) * 8 + ch) * ND + tid];
        c1[tid] = s / (float)len_y[b];
    } else {
        const int d = tid - ND;
        float s = 0.f;
        for (int ch = 0; ch < 8; ++ch)
            s += ws[P_OFF + ((size_t)(1 * NB + b) * 8 + ch) * ND + d];
        c2[d] = s / (float)len_z[b];
    }
    __syncthreads();

    const float* w1s[4] = {W1w1, B1w1, W2w1, B2w1};
    const float* b1s[4] = {W1b1, B1b1, W2b1, B2b1};
    const float* w2s[4] = {W1w2, B1w2, W2w2, B2w2};
    const float* b2s[4] = {W1b2, B1b2, W2b2, B2b2};

    for (int m = 0; m < 4; ++m) {
        const float* c = (m < 2) ? c1 : c2;
        const float* w = w1s[m];
        const int j = tid;
        float s = b1s[m][j];
        for (int i = 0; i < ND; ++i)
            s = fmaf(c[i], w[i * NH + j], s);
        h[m][j] = 0.5f * s * (1.f + erff(s * 0.7071067811865475f));
    }
    __syncthreads();

    for (int p = tid; p < 4 * ND; p += 256) {
        const int m = p >> 7, d = p & 127;
        const float* w = w2s[m];
        float s = b2s[m][d];
        for (int j = 0; j < NH; ++j)
            s = fmaf(h[m][j], w[j * ND + d], s);
        o[m][d] = s;
    }
    __syncthreads();

    if (tid < ND) {
        ws[SCALE_OFF + b * ND + tid] = 1.f + 0.5f * (o[0][tid] + o[2][tid]);
        ws[BIAS_OFF  + b * ND + tid] = 0.5f * (o[1][tid] + o[3][tid]);
    }
}

// ---------------- K3: forward DFT, t-folded (rows k=0..l/2) + real filter + weight ----
// X[k,d] = sum_{s=0..KH} c_s[d]*cos(th*k*s) - i * d_s[d]*sin(th*k*s),  th = 2pi/l
//   c_s = x[s]+x[l-s], d_s = x[s]-x[l-s]  (s=0 and 2s==l: c=x[s], d=0)
// grid: (33 ktiles, 4 dquads, NB), 128 threads = 16 k-rows x 8 dquads; 1 row x 4 d each.
__global__ __launch_bounds__(128) void k_fwd(const float* __restrict__ x,
                                             const int* __restrict__ len_x,
                                             const float* __restrict__ ws_ro,
                                             float* __restrict__ ws) {
    const int b = blockIdx.z;
    const int l = len_x[b];
    const int KH = l >> 1;
    const int kb = blockIdx.x * 16;
    if (kb > KH) return;
    const int dbase = blockIdx.y * 32;

    const int tid = threadIdx.x;
    const int rq = tid >> 3;   // 0..15
    const int dq = tid & 7;    // 0..7
    const int d0 = dbase + dq * 4;
    const float invl = 1.f / (float)l;

    const int k = kb + rq;
    const bool act = (k <= KH);
    const int kc = act ? k : 0;
    float sre, sim;
    sincosf(-TWO_PI * (float)kc * invl, &sim, &sre);

    float ar[4] = {}, ai[4] = {};
    __shared__ float cs[32][32];
    __shared__ float dd[32][32];

    const int NS = KH + 1;  // t-slots
    for (int s0 = 0; s0 < NS; s0 += 32) {
        const int sn = min(32, NS - s0);
        __syncthreads();
        for (int p = tid; p < sn * 8; p += 128) {
            const int row = p >> 3, c4 = (p & 7) << 2;
            const int s = s0 + row;
            const float4 a = *(const float4*)&x[((size_t)b * SL + (size_t)s) * ND + dbase + c4];
            float4 bb = make_float4(0.f, 0.f, 0.f, 0.f);
            if (s > 0 && 2 * s != l)
                bb = *(const float4*)&x[((size_t)b * SL + (size_t)(l - s)) * ND + dbase + c4];
            *(float4*)&cs[row][c4] = make_float4(a.x + bb.x, a.y + bb.y, a.z + bb.z, a.w + bb.w);
            *(float4*)&dd[row][c4] = make_float4(a.x - bb.x, a.y - bb.y, a.z - bb.z, a.w - bb.w);
        }
        __syncthreads();

        const int idx0 = (kc * s0) % l;
        float cre, cim;   // (cos, sin) of -th*k*s
        sincosf(-TWO_PI * (float)idx0 * invl, &cim, &cre);

#pragma unroll 4
        for (int s = 0; s < sn; ++s) {
            const float4 cv = *(const float4*)&cs[s][dq * 4];
            const float4 dv = *(const float4*)&dd[s][dq * 4];
            // re += c*cos(th k s) = c*cre ;  im += -d*sin(th k s) = d*cim
            ar[0] = fmaf(cre, cv.x, ar[0]); ai[0] = fmaf(cim, dv.x, ai[0]);
            ar[1] = fmaf(cre, cv.y, ar[1]); ai[1] = fmaf(cim, dv.y, ai[1]);
            ar[2] = fmaf(cre, cv.z, ar[2]); ai[2] = fmaf(cim, dv.z, ai[2]);
            ar[3] = fmaf(cre, cv.w, ar[3]); ai[3] = fmaf(cim, dv.w, ai[3]);
            const float ncr = fmaf(cre, sre, -cim * sim);
            const float nci = fmaf(cre, sim, cim * sre);
            cre = ncr; cim = nci;
        }
    }

    if (!act) return;
    const float w = (kc == 0 || 2 * kc == l) ? 1.f : 2.f;
    const float4 sc = *(const float4*)&ws_ro[SCALE_OFF + b * ND + d0];
    const float4 bi = *(const float4*)&ws_ro[BIAS_OFF + b * ND + d0];
    const size_t o = (size_t)b * SL * ND + (size_t)kc * ND + d0;
    const float4 fr = make_float4(w * fmaf(ar[0], sc.x, bi.x), w * fmaf(ar[1], sc.y, bi.y),
                                  w * fmaf(ar[2], sc.z, bi.z), w * fmaf(ar[3], sc.w, bi.w));
    const float4 fi = make_float4(w * ai[0] * sc.x, w * ai[1] * sc.y,
                                  w * ai[2] * sc.z, w * ai[3] * sc.w);
    *(float4*)&ws[FILTR_OFF + o] = fr;
    *(float4*)&ws[FILTI_OFF + o] = fi;
}

// ---------------- K4: inverse DFT, t-folded real output ----------------
// A[d] = sum_k Frw[k,d]*cos(th k t), B[d] = sum_k Fiw[k,d]*sin(th k t)
// out[t] = (A-B)/l ; out[l-t] = (A+B)/l  (t>0, 2t!=l)
// grid: (33 ttiles, 4 dquads, NB), 128 threads = 16 t-rows x 8 dquads.
__global__ __launch_bounds__(128) void k_inv(const float* __restrict__ ws,
                                             const int* __restrict__ len_x,
                                             float* __restrict__ out) {
    const int b = blockIdx.z;
    const int l = len_x[b];
    const int KH = l >> 1;
    const int tb = blockIdx.x * 16;
    if (tb > KH) return;
    const int dbase = blockIdx.y * 32;

    const int tid = threadIdx.x;
    const int rq = tid >> 3;
    const int dq = tid & 7;
    const int d0 = dbase + dq * 4;
    const float invl = 1.f / (float)l;

    const int t = tb + rq;
    const bool act = (t <= KH);
    const int tc = act ? t : 0;
    float sre, sim;
    sincosf(TWO_PI * (float)tc * invl, &sim, &sre);

    float A[4] = {}, Bv[4] = {};
    __shared__ float fsr[32][32];
    __shared__ float fsi[32][32];

    for (int k0 = 0; k0 <= KH; k0 += 32) {
        const int kn = min(32, KH + 1 - k0);
        __syncthreads();
        for (int p = tid; p < kn * 8; p += 128) {
            const int row = p >> 3, c4 = (p & 7) << 2;
            const size_t o = (size_t)b * SL * ND + (size_t)(k0 + row) * ND + dbase + c4;
            *(float4*)&fsr[row][c4] = *(const float4*)&ws[FILTR_OFF + o];
            *(float4*)&fsi[row][c4] = *(const float4*)&ws[FILTI_OFF + o];
        }
        __syncthreads();

        const int idx0 = (tc * k0) % l;
        float cre, cim;   // (cos, sin) of +th*k*t
        sincosf(TWO_PI * (float)idx0 * invl, &cim, &cre);

#pragma unroll 4
        for (int kk = 0; kk < kn; ++kk) {
            const float4 ra = *(const float4*)&fsr[kk][dq * 4];
            const float4 ia = *(const float4*)&fsi[kk][dq * 4];
            A[0] = fmaf(cre, ra.x, A[0]); Bv[0] = fmaf(cim, ia.x, Bv[0]);
            A[1] = fmaf(cre, ra.y, A[1]); Bv[1] = fmaf(cim, ia.y, Bv[1]);
            A[2] = fmaf(cre, ra.z, A[2]); Bv[2] = fmaf(cim, ia.z, Bv[2]);
            A[3] = fmaf(cre, ra.w, A[3]); Bv[3] = fmaf(cim, ia.w, Bv[3]);
            const float ncr = fmaf(cre, sre, -cim * sim);
            const float nci = fmaf(cre, sim, cim * sre);
            cre = ncr; cim = nci;
        }
    }

    if (!act) return;
    const float4 va = make_float4((A[0] - Bv[0]) * invl, (A[1] - Bv[1]) * invl,
                                  (A[2] - Bv[2]) * invl, (A[3] - Bv[3]) * invl);
    *(float4*)&out[((size_t)b * SL + (size_t)tc) * ND + d0] = va;
    if (tc > 0 && 2 * tc != l) {
        const float4 vb = make_float4((A[0] + Bv[0]) * invl, (A[1] + Bv[1]) * invl,
                                      (A[2] + Bv[2]) * invl, (A[3] + Bv[3]) * invl);
        *(float4*)&out[((size_t)b * SL + (size_t)(l - tc)) * ND + d0] = vb;
    }
}

extern "C" void kernel_launch(void* const* d_in, const int* in_sizes, int n_in,
                              void* d_out, int out_size, void* d_ws, size_t ws_size,
                              hipStream_t stream) {
    const float* x = (const float*)d_in[0];
    const float* y = (const float*)d_in[1];
    const float* z = (const float*)d_in[2];
    const int* len_x = (const int*)d_in[3];
    const int* len_y = (const int*)d_in[4];
    const int* len_z = (const int*)d_in[5];
    float* ws = (float*)d_ws;
    float* out = (float*)d_out;

    hipMemsetAsync(d_out, 0, (size_t)NB * SL * ND * sizeof(float), stream);

    k_partial<<<2 * NB * 8, 256, 0, stream>>>(y, z, ws);

    k_mlp<<<NB, 256, 0, stream>>>(ws, len_y, len_z,
        (const float*)d_in[6],  (const float*)d_in[7],  (const float*)d_in[8],  (const float*)d_in[9],
        (const float*)d_in[10], (const float*)d_in[11], (const float*)d_in[12], (const float*)d_in[13],
        (const float*)d_in[14], (const float*)d_in[15], (const float*)d_in[16], (const float*)d_in[17],
        (const float*)d_in[18], (const float*)d_in[19], (const float*)d_in[20], (const float*)d_in[21]);

    k_fwd<<<dim3(33, 4, NB), 128, 0, stream>>>(x, len_x, ws, ws);

    k_inv<<<dim3(33, 4, NB), 128, 0, stream>>>(ws, len_x, out);
}

// Round 6
// 85.357 us; speedup vs baseline: 4.0663x; 1.6163x over previous
//
#include <hip/hip_runtime.h>
#include <math.h>

constexpr int NB = 16;    // batch
constexpr int SL = 1024;  // L
constexpr int ND = 128;   // D
constexpr int NH = 256;   // H
constexpr int SPAD = 544; // padded spectrum/time length (17*32)

// bf16 plane layout in ws (ushort element indices)
constexpr size_t PLANE  = (size_t)NB * ND * SPAD;   // 1,114,112 elems
constexpr size_t CS_OFF = 0;                        // cs  [b][d][s]
constexpr size_t DD_OFF = PLANE;                    // dd  [b][d][s]
constexpr size_t FR_OFF = 2 * PLANE;                // Frw [b][d][k]
constexpr size_t FI_OFF = 3 * PLANE;                // Fiw [b][d][k]
// float scratch after the 4 bf16 planes (float element indices)
constexpr size_t F32B      = 2 * PLANE;             // 4 planes * 2B = 2*PLANE floats
constexpr size_t P_OFF     = F32B;                  // [2][16][16][128]
constexpr size_t SCALE_OFF = P_OFF + 2 * 16 * 16 * 128;
constexpr size_t BIAS_OFF  = SCALE_OFF + NB * ND;

constexpr float TWO_PI = 6.283185307179586f;

typedef float          f32x4 __attribute__((ext_vector_type(4)));
typedef unsigned int   u32x4 __attribute__((ext_vector_type(4)));
typedef unsigned short u16x8 __attribute__((ext_vector_type(8)));

__device__ __forceinline__ unsigned short f2bf(float f) {
    unsigned u = __float_as_uint(f);
    return (unsigned short)((u + 0x7FFFu + ((u >> 16) & 1u)) >> 16);
}
__device__ __forceinline__ void mfma16(f32x4& acc, u32x4 a, u32x4 b) {
    asm("v_mfma_f32_16x16x32_bf16 %0, %1, %2, %0" : "+v"(acc) : "v"(a), "v"(b));
}

// ---------------- K1: partial sums of y and z over t ----------------
__global__ __launch_bounds__(256) void k_partial(const float* __restrict__ y,
                                                 const float* __restrict__ z,
                                                 float* __restrict__ ws) {
    const int blk = blockIdx.x;          // 512 = src*256 + b*16 + ch
    const int ch  = blk & 15;
    const int b   = (blk >> 4) & 15;
    const int src = blk >> 8;
    const float* base = (src == 0 ? y : z) + (size_t)b * SL * ND;
    const int d    = threadIdx.x & 127;
    const int half = threadIdx.x >> 7;
    float s = 0.f;
    const int t0 = ch * 64 + half;
    for (int j = 0; j < 32; ++j)
        s += base[(size_t)(t0 + 2 * j) * ND + d];
    __shared__ float red[256];
    red[threadIdx.x] = s;
    __syncthreads();
    if (half == 0)
        ws[P_OFF + ((size_t)((src * NB + b) * 16 + ch)) * ND + d] = s + red[d + 128];
}

// ---------------- K2: MLPs -> scale/bias ----------------
__global__ __launch_bounds__(256) void k_mlp(
    float* __restrict__ ws,
    const int* __restrict__ len_y, const int* __restrict__ len_z,
    const float* __restrict__ W1w1, const float* __restrict__ W1b1,
    const float* __restrict__ W1w2, const float* __restrict__ W1b2,
    const float* __restrict__ B1w1, const float* __restrict__ B1b1,
    const float* __restrict__ B1w2, const float* __restrict__ B1b2,
    const float* __restrict__ W2w1, const float* __restrict__ W2b1,
    const float* __restrict__ W2w2, const float* __restrict__ W2b2,
    const float* __restrict__ B2w1, const float* __restrict__ B2b1,
    const float* __restrict__ B2w2, const float* __restrict__ B2b2) {
    const int b = blockIdx.x;
    const int tid = threadIdx.x;
    __shared__ float c1[ND], c2[ND];
    __shared__ float h[4][NH];
    __shared__ float o[4][ND];

    if (tid < ND) {
        float s = 0.f;
        for (int ch = 0; ch < 16; ++ch)
            s += ws[P_OFF + ((size_t)((0 * NB + b) * 16 + ch)) * ND + tid];
        c1[tid] = s / (float)len_y[b];
    } else {
        const int d = tid - ND;
        float s = 0.f;
        for (int ch = 0; ch < 16; ++ch)
            s += ws[P_OFF + ((size_t)((1 * NB + b) * 16 + ch)) * ND + d];
        c2[d] = s / (float)len_z[b];
    }
    __syncthreads();

    const float* w1s[4] = {W1w1, B1w1, W2w1, B2w1};
    const float* b1s[4] = {W1b1, B1b1, W2b1, B2b1};
    const float* w2s[4] = {W1w2, B1w2, W2w2, B2w2};
    const float* b2s[4] = {W1b2, B1b2, W2b2, B2b2};

    for (int m = 0; m < 4; ++m) {
        const float* c = (m < 2) ? c1 : c2;
        const float* w = w1s[m];
        const int j = tid;
        float s = b1s[m][j];
        for (int i = 0; i < ND; ++i)
            s = fmaf(c[i], w[i * NH + j], s);
        h[m][j] = 0.5f * s * (1.f + erff(s * 0.7071067811865475f));
    }
    __syncthreads();

    for (int p = tid; p < 4 * ND; p += 256) {
        const int m = p >> 7, d = p & 127;
        const float* w = w2s[m];
        float s = b2s[m][d];
        for (int j = 0; j < NH; ++j)
            s = fmaf(h[m][j], w[j * ND + d], s);
        o[m][d] = s;
    }
    __syncthreads();

    if (tid < ND) {
        ws[SCALE_OFF + b * ND + tid] = 1.f + 0.5f * (o[0][tid] + o[2][tid]);
        ws[BIAS_OFF  + b * ND + tid] = 0.5f * (o[1][tid] + o[3][tid]);
    }
}

// ---------------- K3: fold x -> cs/dd bf16 planes [b][d][s] ----------------
// grid (17, NB), 256 thr: thread = (d = tid&127, slot = tid>>7); covers 32 s per block.
__global__ __launch_bounds__(256) void k_prep(const float* __restrict__ x,
                                              const int* __restrict__ len_x,
                                              unsigned short* __restrict__ wsb) {
    const int b = blockIdx.y;
    const int l = len_x[b];
    const int NS = (l >> 1) + 1;
    const int d = threadIdx.x & 127;
    const int slot = threadIdx.x >> 7;
#pragma unroll
    for (int it = 0; it < 2; ++it) {
        const int sb = (blockIdx.x * 4 + slot * 2 + it) * 8;
        u16x8 cb, db;
#pragma unroll
        for (int j = 0; j < 8; ++j) {
            const int s = sb + j;
            float c = 0.f, dd = 0.f;
            if (s < NS) {
                const float a = x[((size_t)b * SL + s) * ND + d];
                float p = 0.f;
                if (s > 0 && 2 * s != l) p = x[((size_t)b * SL + (l - s)) * ND + d];
                c = a + p; dd = a - p;
            }
            cb[j] = f2bf(c); db[j] = f2bf(dd);
        }
        const size_t ro = ((size_t)b * ND + d) * SPAD + sb;
        *(u16x8*)&wsb[CS_OFF + ro] = cb;
        *(u16x8*)&wsb[DD_OFF + ro] = db;
    }
}

// ---------------- K4: forward DFT via MFMA + filter -> Frw/Fiw planes ----------------
// grid (33 ktiles, NB), 256 thr = 4 waves; wave w: d in [32w, 32w+32), k-tile shared (16).
// X^T[d,k]: re = sum_s cs[d,s]*cos(th k s); im = sum_s dd[d,s]*(-sin(th k s))
__global__ __launch_bounds__(256) void k_fwd(const int* __restrict__ len_x,
                                             const float* __restrict__ wsf,
                                             unsigned short* __restrict__ wsb) {
    const int b = blockIdx.y;
    const int l = len_x[b];
    const int NS = (l >> 1) + 1;
    const int kbase = blockIdx.x * 16;
    if (kbase >= NS) return;
    const float invl = 1.f / (float)l;
    const float fl = (float)l;

    __shared__ __align__(16) unsigned short Ec[16][40];
    __shared__ __align__(16) unsigned short Es[16][40];

    const int tid = threadIdx.x;
    const int lane = tid & 63, wave = tid >> 6;
    const int dbase = wave * 32;
    const int lrow = lane & 15, lkg = lane >> 4;

    f32x4 accR[2], accI[2];
#pragma unroll
    for (int t = 0; t < 2; ++t) {
        accR[t] = 0.f; accI[t] = 0.f;
    }

    for (int s0 = 0; s0 < NS; s0 += 32) {
        __syncthreads();
#pragma unroll
        for (int pp = 0; pp < 2; ++pp) {
            const int p = tid + pp * 256;
            const int kk = p >> 5, ss = p & 31;
            const int sg = s0 + ss;
            float cv = 0.f, sv = 0.f;
            if (sg < NS) {
                const float ks = (float)((kbase + kk) * sg);
                const float q = floorf(ks * invl);
                const float idxf = fmaf(-fl, q, ks);     // (k*s) mod l  (maybe -l off: ok)
                float s_, c_;
                sincosf(-TWO_PI * idxf * invl, &s_, &c_); // c_=cos, s_=-sin
                cv = c_; sv = s_;
            }
            Ec[kk][ss] = f2bf(cv);
            Es[kk][ss] = f2bf(sv);
        }
        __syncthreads();

        const u32x4 eC = *(const u32x4*)&Ec[lrow][lkg * 8];
        const u32x4 eS = *(const u32x4*)&Es[lrow][lkg * 8];
#pragma unroll
        for (int t = 0; t < 2; ++t) {
            const int drow = dbase + t * 16 + lrow;
            const size_t ro = ((size_t)b * ND + drow) * SPAD + s0 + lkg * 8;
            const u32x4 aC = *(const u32x4*)&wsb[CS_OFF + ro];
            const u32x4 aD = *(const u32x4*)&wsb[DD_OFF + ro];
            mfma16(accR[t], aC, eC);
            mfma16(accI[t], aD, eS);
        }
    }

    const int kcol = kbase + lrow;
    if (kcol >= NS) return;
    const float w = (kcol == 0 || 2 * kcol == l) ? 1.f : 2.f;
#pragma unroll
    for (int t = 0; t < 2; ++t) {
#pragma unroll
        for (int r = 0; r < 4; ++r) {
            const int drow = dbase + t * 16 + lkg * 4 + r;
            const float sc = wsf[SCALE_OFF + b * ND + drow];
            const float bi = wsf[BIAS_OFF + b * ND + drow];
            const size_t o = ((size_t)b * ND + drow) * SPAD + kcol;
            wsb[FR_OFF + o] = f2bf(w * fmaf(accR[t][r], sc, bi));
            wsb[FI_OFF + o] = f2bf(w * accI[t][r] * sc);
        }
    }
}

// ---------------- K5: inverse DFT via MFMA, t-folded real output ----------------
// grid (33 ttiles, NB), 256 thr = 4 waves; wave w: d in [32w, 32w+32), t-tile shared.
// A[t,d] = sum_k E2c[t,k]*Frw[k,d]; B[t,d] = sum_k E2s[t,k]*Fiw[k,d]
// out[t] = (A-B)/l ; out[l-t] = (A+B)/l
__global__ __launch_bounds__(256) void k_inv(const int* __restrict__ len_x,
                                             const unsigned short* __restrict__ wsb,
                                             float* __restrict__ out) {
    const int b = blockIdx.y;
    const int l = len_x[b];
    const int NS = (l >> 1) + 1;
    const int tbase = blockIdx.x * 16;
    if (tbase >= NS) return;
    const float invl = 1.f / (float)l;
    const float fl = (float)l;

    __shared__ __align__(16) unsigned short E2c[16][40];
    __shared__ __align__(16) unsigned short E2s[16][40];

    const int tid = threadIdx.x;
    const int lane = tid & 63, wave = tid >> 6;
    const int dbase = wave * 32;
    const int lrow = lane & 15, lkg = lane >> 4;

    f32x4 accA[2], accB[2];
#pragma unroll
    for (int t = 0; t < 2; ++t) {
        accA[t] = 0.f; accB[t] = 0.f;
    }

    for (int k0 = 0; k0 < NS; k0 += 32) {
        __syncthreads();
#pragma unroll
        for (int pp = 0; pp < 2; ++pp) {
            const int p = tid + pp * 256;
            const int tt = p >> 5, kk = p & 31;
            const int kg = k0 + kk;
            float cv = 0.f, sv = 0.f;
            if (kg < NS) {
                const float tk = (float)((tbase + tt) * kg);
                const float q = floorf(tk * invl);
                const float idxf = fmaf(-fl, q, tk);
                float s_, c_;
                sincosf(TWO_PI * idxf * invl, &s_, &c_);  // +sin
                cv = c_; sv = s_;
            }
            E2c[tt][kk] = f2bf(cv);
            E2s[tt][kk] = f2bf(sv);
        }
        __syncthreads();

        const u32x4 aC = *(const u32x4*)&E2c[lrow][lkg * 8];
        const u32x4 aS = *(const u32x4*)&E2s[lrow][lkg * 8];
#pragma unroll
        for (int t = 0; t < 2; ++t) {
            const int dcol = dbase + t * 16 + lrow;
            const size_t ro = ((size_t)b * ND + dcol) * SPAD + k0 + lkg * 8;
            const u32x4 bR = *(const u32x4*)&wsb[FR_OFF + ro];
            const u32x4 bI = *(const u32x4*)&wsb[FI_OFF + ro];
            mfma16(accA[t], aC, bR);
            mfma16(accB[t], aS, bI);
        }
    }

#pragma unroll
    for (int t = 0; t < 2; ++t) {
#pragma unroll
        for (int r = 0; r < 4; ++r) {
            const int trow = tbase + lkg * 4 + r;
            if (trow >= NS) continue;
            const int dcol = dbase + t * 16 + lrow;
            const float vA = accA[t][r], vB = accB[t][r];
            out[((size_t)b * SL + trow) * ND + dcol] = (vA - vB) * invl;
            if (trow > 0 && 2 * trow != l)
                out[((size_t)b * SL + (l - trow)) * ND + dcol] = (vA + vB) * invl;
        }
    }
}

extern "C" void kernel_launch(void* const* d_in, const int* in_sizes, int n_in,
                              void* d_out, int out_size, void* d_ws, size_t ws_size,
                              hipStream_t stream) {
    const float* x = (const float*)d_in[0];
    const float* y = (const float*)d_in[1];
    const float* z = (const float*)d_in[2];
    const int* len_x = (const int*)d_in[3];
    const int* len_y = (const int*)d_in[4];
    const int* len_z = (const int*)d_in[5];
    float* wsf = (float*)d_ws;
    unsigned short* wsb = (unsigned short*)d_ws;
    float* out = (float*)d_out;

    hipMemsetAsync(d_out, 0, (size_t)NB * SL * ND * sizeof(float), stream);

    k_partial<<<512, 256, 0, stream>>>(y, z, wsf);

    k_mlp<<<NB, 256, 0, stream>>>(wsf, len_y, len_z,
        (const float*)d_in[6],  (const float*)d_in[7],  (const float*)d_in[8],  (const float*)d_in[9],
        (const float*)d_in[10], (const float*)d_in[11], (const float*)d_in[12], (const float*)d_in[13],
        (const float*)d_in[14], (const float*)d_in[15], (const float*)d_in[16], (const float*)d_in[17],
        (const float*)d_in[18], (const float*)d_in[19], (const float*)d_in[20], (const float*)d_in[21]);

    k_prep<<<dim3(17, NB), 256, 0, stream>>>(x, len_x, wsb);

    k_fwd<<<dim3(33, NB), 256, 0, stream>>>(len_x, wsf, wsb);

    k_inv<<<dim3(33, NB), 256, 0, stream>>>(len_x, wsb, out);
}